// Round 2
// baseline (330.063 us; speedup 1.0000x reference)
//
#include <hip/hip_runtime.h>

// GPT-2 attention block, MI355X/gfx950.
// Pipeline: cvt(x)->bf16 | transpose(w_attn,w_proj)->bf16 [N,K] |
//           QKV GEMM (bf16 MFMA, epilogue scatters q*0.125,k,v to [B,H,S,HD]) |
//           flash attention (4 waves/block, 16 q-rows/wave, KV tile 32) |
//           proj GEMM (bf16 MFMA, fp32 out + bias)
#define Bn 2
#define Sn 2048
#define Dn 1024
#define Hn 16
#define HDn 64

typedef unsigned short u16;
typedef u16 u16x4 __attribute__((ext_vector_type(4)));
typedef u16 u16x8 __attribute__((ext_vector_type(8)));
typedef __bf16 bf16x8 __attribute__((ext_vector_type(8)));
typedef float f32x4 __attribute__((ext_vector_type(4)));

__device__ __forceinline__ u16 f2bf(float f) {
  union { float f; unsigned u; } v; v.f = f;
  unsigned r = v.u + 0x7fffu + ((v.u >> 16) & 1u);
  return (u16)(r >> 16);
}

__device__ __forceinline__ f32x4 mfma16(u16x8 a, u16x8 b, f32x4 c) {
  return __builtin_amdgcn_mfma_f32_16x16x32_bf16(
      __builtin_bit_cast(bf16x8, a), __builtin_bit_cast(bf16x8, b), c, 0, 0, 0);
}

// ---------------- fp32 -> bf16 elementwise (vectorized) ----------------
__global__ __launch_bounds__(256) void k_cvt(const float* __restrict__ in,
                                             u16* __restrict__ out, int n4) {
  int i = blockIdx.x * 256 + threadIdx.x;
  if (i < n4) {
    const float4 v = reinterpret_cast<const float4*>(in)[i];
    u16x4 o = {f2bf(v.x), f2bf(v.y), f2bf(v.z), f2bf(v.w)};
    reinterpret_cast<u16x4*>(out)[i] = o;
  }
}

// ---------------- fp32 [K,N] -> bf16 [N,K] tiled transpose ----------------
__global__ __launch_bounds__(256) void k_transpose(const float* __restrict__ in,
                                                   u16* __restrict__ out,
                                                   int K, int N) {
  __shared__ u16 tile[32][33];
  const int n0 = blockIdx.x * 32, k0 = blockIdx.y * 32;
  const int tx = threadIdx.x, ty = threadIdx.y;
#pragma unroll
  for (int r = 0; r < 4; ++r) {
    const int k = ty * 4 + r;
    tile[k][tx] = f2bf(in[(size_t)(k0 + k) * N + n0 + tx]);
  }
  __syncthreads();
#pragma unroll
  for (int r = 0; r < 4; ++r) {
    const int n = ty * 4 + r;
    out[(size_t)(n0 + n) * K + k0 + tx] = tile[tx][n];
  }
}

// ---------------- bf16 GEMM  C[M,N] = A[M,K] * Bt[N,K]^T ----------------
// 128x128 tile, 4 waves (2x2 of 64x64), BK=32, m97 structure.
// mode 0: qkv epilogue (bias, q*=0.125, scatter to q/k/v [B,H,S,HD] bf16)
// mode 1: proj epilogue (bias, fp32 out row-major)
__global__ __launch_bounds__(256) void k_gemm_bt(
    const u16* __restrict__ A, const u16* __restrict__ Bt, int K,
    const float* __restrict__ bias, u16* __restrict__ oq, u16* __restrict__ ok,
    u16* __restrict__ ov, float* __restrict__ of, int mode) {
  __shared__ __align__(16) u16 a_lds[128 * 32];
  __shared__ __align__(16) u16 b_lds[128 * 32];
  const int tid = threadIdx.x;
  const int lane = tid & 63, w = tid >> 6;
  const int wr = w >> 1, wc = w & 1;
  const int lm = lane & 15, lk = lane >> 4;
  const int m0 = blockIdx.y * 128, n0 = blockIdx.x * 128;

  f32x4 acc[4][4] = {};

  for (int k0 = 0; k0 < K; k0 += 32) {
#pragma unroll
    for (int p = 0; p < 2; ++p) {
      const int e = p * 2048 + w * 512 + lane * 8;
      const int row = e >> 5, col = e & 31;
      __builtin_amdgcn_global_load_lds(
          (const __attribute__((address_space(1))) void*)(A + (size_t)(m0 + row) * K + k0 + col),
          (__attribute__((address_space(3))) void*)(a_lds + p * 2048 + w * 512),
          16, 0, 0);
      __builtin_amdgcn_global_load_lds(
          (const __attribute__((address_space(1))) void*)(Bt + (size_t)(n0 + row) * K + k0 + col),
          (__attribute__((address_space(3))) void*)(b_lds + p * 2048 + w * 512),
          16, 0, 0);
    }
    __syncthreads();
    u16x8 av[4], bv[4];
#pragma unroll
    for (int m = 0; m < 4; ++m)
      av[m] = *reinterpret_cast<const u16x8*>(a_lds + (wr * 64 + m * 16 + lm) * 32 + lk * 8);
#pragma unroll
    for (int n = 0; n < 4; ++n)
      bv[n] = *reinterpret_cast<const u16x8*>(b_lds + (wc * 64 + n * 16 + lm) * 32 + lk * 8);
#pragma unroll
    for (int m = 0; m < 4; ++m)
#pragma unroll
      for (int n = 0; n < 4; ++n)
        acc[m][n] = mfma16(av[m], bv[n], acc[m][n]);
    __syncthreads();
  }

#pragma unroll
  for (int m = 0; m < 4; ++m) {
#pragma unroll
    for (int n = 0; n < 4; ++n) {
      const int col = n0 + wc * 64 + n * 16 + lm;
      const float bb = bias[col];
#pragma unroll
      for (int j = 0; j < 4; ++j) {
        const int row = m0 + wr * 64 + m * 16 + lk * 4 + j;
        float val = acc[m][n][j] + bb;
        if (mode == 0) {
          const int which = col >> 10;
          const int h = (col >> 6) & 15, hd = col & 63;
          if (which == 0) val *= 0.125f;  // 1/sqrt(HD), exact in bf16
          const int b = row >> 11, s = row & 2047;
          const size_t idx = (((size_t)(b * Hn + h)) * Sn + s) * HDn + hd;
          u16* dst = which == 0 ? oq : (which == 1 ? ok : ov);
          dst[idx] = f2bf(val);
        } else {
          of[(size_t)row * Dn + col] = val;
        }
      }
    }
  }
}

// ---------------- causal flash attention ----------------
// grid: B*H*(S/64); 4 waves/block; wave w owns q rows [q0, q0+16).
// KV tile = 32 cols; online softmax state per q-row (4 regs/lane).
__global__ __launch_bounds__(256) void k_attn(const u16* __restrict__ qb,
                                              const u16* __restrict__ kb,
                                              const u16* __restrict__ vb,
                                              u16* __restrict__ ob) {
  const int wg = blockIdx.x;
  const int qt = wg & 31, h = (wg >> 5) & 15, b = wg >> 9;
  const int tid = threadIdx.x, lane = tid & 63, w = tid >> 6;
  const int lm = lane & 15, lk = lane >> 4;
  const int q0 = qt * 64 + w * 16;
  const size_t head = (size_t)(b * Hn + h) * Sn * HDn;
  const u16* Q = qb + head;
  const u16* Kp = kb + head;
  const u16* Vp = vb + head;

  __shared__ __align__(16) u16 p_lds[4][16 * 32];
  u16* myp = p_lds[w];

  u16x8 aq[2];
#pragma unroll
  for (int c = 0; c < 2; ++c)
    aq[c] = *reinterpret_cast<const u16x8*>(Q + (size_t)(q0 + lm) * HDn + c * 32 + lk * 8);

  f32x4 o_acc[4] = {};
  float mrow[4], lrow[4];
#pragma unroll
  for (int r = 0; r < 4; ++r) { mrow[r] = -1e30f; lrow[r] = 0.f; }

  const int jmax = q0 + 15;
  for (int j0 = 0; j0 <= jmax; j0 += 32) {
    f32x4 s0 = {}, s1 = {};
#pragma unroll
    for (int c = 0; c < 2; ++c) {
      const u16x8 kf0 = *reinterpret_cast<const u16x8*>(Kp + (size_t)(j0 + lm) * HDn + c * 32 + lk * 8);
      const u16x8 kf1 = *reinterpret_cast<const u16x8*>(Kp + (size_t)(j0 + 16 + lm) * HDn + c * 32 + lk * 8);
      s0 = mfma16(aq[c], kf0, s0);
      s1 = mfma16(aq[c], kf1, s1);
    }
    if (j0 + 31 > q0) {  // causal edge tile
#pragma unroll
      for (int j = 0; j < 4; ++j) {
        const int rowg = q0 + lk * 4 + j;
        if (j0 + lm > rowg) s0[j] = -1e30f;
        if (j0 + 16 + lm > rowg) s1[j] = -1e30f;
      }
    }
    float alpha[4];
#pragma unroll
    for (int r = 0; r < 4; ++r) {
      float v = fmaxf(s0[r], s1[r]);
#pragma unroll
      for (int d = 1; d < 16; d <<= 1) v = fmaxf(v, __shfl_xor(v, d, 64));
      const float mnew = fmaxf(mrow[r], v);
      alpha[r] = exp2f((mrow[r] - mnew) * 1.44269504f);
      mrow[r] = mnew;
      const float p0 = exp2f((s0[r] - mnew) * 1.44269504f);
      const float p1 = exp2f((s1[r] - mnew) * 1.44269504f);
      myp[(lk * 4 + r) * 32 + lm] = f2bf(p0);
      myp[(lk * 4 + r) * 32 + 16 + lm] = f2bf(p1);
      float ps = p0 + p1;
#pragma unroll
      for (int d = 1; d < 16; d <<= 1) ps += __shfl_xor(ps, d, 64);
      lrow[r] = lrow[r] * alpha[r] + ps;
    }
#pragma unroll
    for (int t = 0; t < 4; ++t)
#pragma unroll
      for (int j = 0; j < 4; ++j) o_acc[t][j] *= alpha[j];

    const u16x8 pa = *reinterpret_cast<const u16x8*>(myp + lm * 32 + lk * 8);
#pragma unroll
    for (int t = 0; t < 4; ++t) {
      u16x8 vf;
#pragma unroll
      for (int i = 0; i < 8; ++i)
        vf[i] = Vp[(size_t)(j0 + lk * 8 + i) * HDn + t * 16 + lm];
      o_acc[t] = mfma16(pa, vf, o_acc[t]);
    }
  }

#pragma unroll
  for (int t = 0; t < 4; ++t) {
#pragma unroll
    for (int j = 0; j < 4; ++j) {
      const int rowg = q0 + lk * 4 + j;
      const float val = o_acc[t][j] / lrow[j];
      ob[((size_t)(b * Sn + rowg)) * Dn + h * HDn + t * 16 + lm] = f2bf(val);
    }
  }
}

extern "C" void kernel_launch(void* const* d_in, const int* in_sizes, int n_in,
                              void* d_out, int out_size, void* d_ws, size_t ws_size,
                              hipStream_t stream) {
  const float* x = (const float*)d_in[0];
  const float* w_attn = (const float*)d_in[1];
  const float* b_attn = (const float*)d_in[2];
  const float* w_proj = (const float*)d_in[3];
  const float* b_proj = (const float*)d_in[4];
  float* out = (float*)d_out;

  // workspace layout (u16 elements), ~48 MB total
  u16* ws = (u16*)d_ws;
  u16* xb = ws;                                  // [4096,1024]
  u16* wat = xb + (size_t)4096 * 1024;           // [3072,1024]  (w_attn^T)
  u16* wpt = wat + (size_t)3072 * 1024;          // [1024,1024]  (w_proj^T)
  u16* qb = wpt + (size_t)1024 * 1024;           // [B,H,S,HD]
  u16* kb = qb + (size_t)Bn * Hn * Sn * HDn;
  u16* vb = kb + (size_t)Bn * Hn * Sn * HDn;
  u16* ao = vb + (size_t)Bn * Hn * Sn * HDn;     // [4096,1024]

  k_cvt<<<4096, 256, 0, stream>>>(x, xb, 1048576);
  k_transpose<<<dim3(3072 / 32, 1024 / 32), dim3(32, 8), 0, stream>>>(w_attn, wat, 1024, 3072);
  k_transpose<<<dim3(1024 / 32, 1024 / 32), dim3(32, 8), 0, stream>>>(w_proj, wpt, 1024, 1024);
  k_gemm_bt<<<dim3(3072 / 128, 4096 / 128), 256, 0, stream>>>(xb, wat, 1024, b_attn, qb, kb, vb, nullptr, 0);
  k_attn<<<Bn * Hn * (Sn / 64), 256, 0, stream>>>(qb, kb, vb, ao);
  k_gemm_bt<<<dim3(1024 / 128, 4096 / 128), 256, 0, stream>>>(ao, wpt, 1024, b_proj, nullptr, nullptr, nullptr, out, 1);
}

// Round 4
// 205.981 us; speedup vs baseline: 1.6024x; 1.6024x over previous
//
#include <hip/hip_runtime.h>

// GPT-2 attention block, MI355X/gfx950.
// cvt(x)->bf16 | transpose(w)->bf16 [N,K] | QKV GEMM (scatter q*0.125,k,v) |
// flash attention (swapped QK^T, LDS-staged K/V^T, XOR swizzle) | proj GEMM
#define Bn 2
#define Sn 2048
#define Dn 1024
#define Hn 16
#define HDn 64

typedef unsigned short u16;
typedef u16 u16x4 __attribute__((ext_vector_type(4)));
typedef u16 u16x8 __attribute__((ext_vector_type(8)));
typedef __bf16 bf16x8 __attribute__((ext_vector_type(8)));
typedef float f32x4 __attribute__((ext_vector_type(4)));

__device__ __forceinline__ u16 f2bf(float f) {
  union { float f; unsigned u; } v; v.f = f;
  unsigned r = v.u + 0x7fffu + ((v.u >> 16) & 1u);
  return (u16)(r >> 16);
}

__device__ __forceinline__ f32x4 mfma16(u16x8 a, u16x8 b, f32x4 c) {
  return __builtin_amdgcn_mfma_f32_16x16x32_bf16(
      __builtin_bit_cast(bf16x8, a), __builtin_bit_cast(bf16x8, b), c, 0, 0, 0);
}

// XOR swizzle for 128B-stride LDS tiles: conflict-free for row-varying-lane
// b128 reads AND the V^T transposed b16 writes (row-index bits folded in).
__device__ __forceinline__ int swzb(int row, int bytecol) {
  return row * 128 + (bytecol ^ ((((row & 7) ^ ((row >> 3) & 7))) << 4));
}

// ---------------- fp32 -> bf16 elementwise (vectorized) ----------------
__global__ __launch_bounds__(256) void k_cvt(const float* __restrict__ in,
                                             u16* __restrict__ out, int n4) {
  int i = blockIdx.x * 256 + threadIdx.x;
  if (i < n4) {
    const float4 v = reinterpret_cast<const float4*>(in)[i];
    u16x4 o = {f2bf(v.x), f2bf(v.y), f2bf(v.z), f2bf(v.w)};
    reinterpret_cast<u16x4*>(out)[i] = o;
  }
}

// ---------------- fp32 [K,N] -> bf16 [N,K] tiled transpose ----------------
__global__ __launch_bounds__(256) void k_transpose(const float* __restrict__ in,
                                                   u16* __restrict__ out,
                                                   int K, int N) {
  __shared__ u16 tile[32][33];
  const int n0 = blockIdx.x * 32, k0 = blockIdx.y * 32;
  const int tx = threadIdx.x, ty = threadIdx.y;
#pragma unroll
  for (int r = 0; r < 4; ++r) {
    const int k = ty * 4 + r;
    tile[k][tx] = f2bf(in[(size_t)(k0 + k) * N + n0 + tx]);
  }
  __syncthreads();
#pragma unroll
  for (int r = 0; r < 4; ++r) {
    const int n = ty * 4 + r;
    out[(size_t)(n0 + n) * K + k0 + tx] = tile[tx][n];
  }
}

// ---------------- bf16 GEMM  C[M,N] = A[M,K] * Bt[N,K]^T ----------------
__global__ __launch_bounds__(256) void k_gemm_bt(
    const u16* __restrict__ A, const u16* __restrict__ Bt, int K,
    const float* __restrict__ bias, u16* __restrict__ oq, u16* __restrict__ ok,
    u16* __restrict__ ov, float* __restrict__ of, int mode) {
  __shared__ __align__(16) u16 a_lds[128 * 32];
  __shared__ __align__(16) u16 b_lds[128 * 32];
  const int tid = threadIdx.x;
  const int lane = tid & 63, w = tid >> 6;
  const int wr = w >> 1, wc = w & 1;
  const int lm = lane & 15, lk = lane >> 4;
  const int m0 = blockIdx.y * 128, n0 = blockIdx.x * 128;

  f32x4 acc[4][4] = {};

  for (int k0 = 0; k0 < K; k0 += 32) {
#pragma unroll
    for (int p = 0; p < 2; ++p) {
      const int e = p * 2048 + w * 512 + lane * 8;
      const int row = e >> 5, col = e & 31;
      __builtin_amdgcn_global_load_lds(
          (const __attribute__((address_space(1))) void*)(A + (size_t)(m0 + row) * K + k0 + col),
          (__attribute__((address_space(3))) void*)(a_lds + p * 2048 + w * 512),
          16, 0, 0);
      __builtin_amdgcn_global_load_lds(
          (const __attribute__((address_space(1))) void*)(Bt + (size_t)(n0 + row) * K + k0 + col),
          (__attribute__((address_space(3))) void*)(b_lds + p * 2048 + w * 512),
          16, 0, 0);
    }
    __syncthreads();
    u16x8 av[4], bv[4];
#pragma unroll
    for (int m = 0; m < 4; ++m)
      av[m] = *reinterpret_cast<const u16x8*>(a_lds + (wr * 64 + m * 16 + lm) * 32 + lk * 8);
#pragma unroll
    for (int n = 0; n < 4; ++n)
      bv[n] = *reinterpret_cast<const u16x8*>(b_lds + (wc * 64 + n * 16 + lm) * 32 + lk * 8);
#pragma unroll
    for (int m = 0; m < 4; ++m)
#pragma unroll
      for (int n = 0; n < 4; ++n)
        acc[m][n] = mfma16(av[m], bv[n], acc[m][n]);
    __syncthreads();
  }

#pragma unroll
  for (int m = 0; m < 4; ++m) {
#pragma unroll
    for (int n = 0; n < 4; ++n) {
      const int col = n0 + wc * 64 + n * 16 + lm;
      const float bb = bias[col];
#pragma unroll
      for (int j = 0; j < 4; ++j) {
        const int row = m0 + wr * 64 + m * 16 + lk * 4 + j;
        float val = acc[m][n][j] + bb;
        if (mode == 0) {
          const int which = col >> 10;
          const int h = (col >> 6) & 15, hd = col & 63;
          if (which == 0) val *= 0.125f;
          const int b = row >> 11, s = row & 2047;
          const size_t idx = (((size_t)(b * Hn + h)) * Sn + s) * HDn + hd;
          u16* dst = which == 0 ? oq : (which == 1 ? ok : ov);
          dst[idx] = f2bf(val);
        } else {
          of[(size_t)row * Dn + col] = val;
        }
      }
    }
  }
}

// ---------------- causal flash attention (v2) ----------------
// grid: B*H*(S/64), longest-q-tile-first. 4 waves/block, wave = 16 q-rows.
// KV tile = 64. Swapped QK^T (S^T = K·Q^T) so softmax is lane-local (16
// vals/lane, one q-row) + 2 shuffles. K staged row-major, V staged
// TRANSPOSED, both XOR-swizzled; P bounced through per-wave LDS into
// MFMA-A layout. Next tile's global loads issued before compute (T14).
__global__ __launch_bounds__(256) void k_attn(const u16* __restrict__ qb,
                                              const u16* __restrict__ kb,
                                              const u16* __restrict__ vb,
                                              u16* __restrict__ ob) {
  const int bx = blockIdx.x;
  const int qt = 31 - (bx >> 5);   // longest blocks first
  const int bh = bx & 31;
  const int h = bh & 15, b = bh >> 4;
  const int tid = threadIdx.x, lane = tid & 63, w = tid >> 6;
  const int lm = lane & 15, lk = lane >> 4;
  const int Q0 = qt * 64;
  const int q0 = Q0 + w * 16;
  const size_t head = (size_t)(b * Hn + h) * Sn * HDn;
  const u16* Q = qb + head;
  const u16* Kp = kb + head;
  const u16* Vp = vb + head;

  __shared__ __align__(16) u16 k_lds[64 * 64];
  __shared__ __align__(16) u16 vt_lds[64 * 64];
  __shared__ __align__(16) u16 p_lds[4][16 * 64];
  char* myp = (char*)p_lds[w];

  // staging map: thread -> row sr, col-block scb (2x u16x8 per thread)
  const int sr = tid >> 2, scb = (tid & 3) * 16;
  const u16* Ksrc = Kp + (size_t)sr * HDn + scb;
  const u16* Vsrc = Vp + (size_t)sr * HDn + scb;

  // Q fragments (B-operand of swapped QK^T == A-operand layout rows)
  u16x8 aq[2];
#pragma unroll
  for (int c = 0; c < 2; ++c)
    aq[c] = *reinterpret_cast<const u16x8*>(Q + (size_t)(q0 + lm) * HDn + c * 32 + lk * 8);

  f32x4 o_acc[4] = {};
  float mrow = -1e30f, lrow = 0.f;  // softmax state for q-row q0+lm
  const float C = 1.44269504f;

  const int nk = Q0 + 64;  // block's causal k extent
  u16x8 kreg[2], vreg[2];
  // prologue: stage tile 0 into regs
  kreg[0] = *reinterpret_cast<const u16x8*>(Ksrc);
  kreg[1] = *reinterpret_cast<const u16x8*>(Ksrc + 8);
  vreg[0] = *reinterpret_cast<const u16x8*>(Vsrc);
  vreg[1] = *reinterpret_cast<const u16x8*>(Vsrc + 8);

  for (int j0 = 0; j0 < nk; j0 += 64) {
    // write staged regs -> LDS (K row-major, V transposed), swizzled
    *reinterpret_cast<u16x8*>((char*)k_lds + swzb(sr, scb * 2)) = kreg[0];
    *reinterpret_cast<u16x8*>((char*)k_lds + swzb(sr, scb * 2 + 16)) = kreg[1];
#pragma unroll
    for (int i = 0; i < 8; ++i) {
      *reinterpret_cast<u16*>((char*)vt_lds + swzb(scb + i, sr * 2)) = vreg[0][i];
      *reinterpret_cast<u16*>((char*)vt_lds + swzb(scb + 8 + i, sr * 2)) = vreg[1][i];
    }
    __syncthreads();
    if (j0 + 64 < nk) {  // issue next tile loads; latency hides under compute
      const u16* kn = Ksrc + (size_t)(j0 + 64) * HDn;
      const u16* vn = Vsrc + (size_t)(j0 + 64) * HDn;
      kreg[0] = *reinterpret_cast<const u16x8*>(kn);
      kreg[1] = *reinterpret_cast<const u16x8*>(kn + 8);
      vreg[0] = *reinterpret_cast<const u16x8*>(vn);
      vreg[1] = *reinterpret_cast<const u16x8*>(vn + 8);
    }

    // ---- QK^T (swapped): S^T[k][q], lane holds S[q0+lm][j0+kc*16+lk*4+jj]
    f32x4 s[4];
#pragma unroll
    for (int kc = 0; kc < 4; ++kc) {
      const u16x8 kf0 = *reinterpret_cast<const u16x8*>((char*)k_lds + swzb(kc * 16 + lm, lk * 16));
      const u16x8 kf1 = *reinterpret_cast<const u16x8*>((char*)k_lds + swzb(kc * 16 + lm, 64 + lk * 16));
      f32x4 z = {};
      z = mfma16(kf0, aq[0], z);
      s[kc] = mfma16(kf1, aq[1], z);
    }
    if (j0 + 63 > q0) {  // causal mask (diagonal tiles only)
#pragma unroll
      for (int kc = 0; kc < 4; ++kc)
#pragma unroll
        for (int jj = 0; jj < 4; ++jj)
          if (j0 + kc * 16 + lk * 4 + jj > q0 + lm) s[kc][jj] = -1e30f;
    }

    // ---- online softmax (lane-local row) ----
    float vmax = -1e30f;
#pragma unroll
    for (int kc = 0; kc < 4; ++kc)
#pragma unroll
      for (int jj = 0; jj < 4; ++jj) vmax = fmaxf(vmax, s[kc][jj]);
    vmax = fmaxf(vmax, __shfl_xor(vmax, 16, 64));
    vmax = fmaxf(vmax, __shfl_xor(vmax, 32, 64));
    const float mnew = fmaxf(mrow, vmax);
    const float alpha = exp2f((mrow - mnew) * C);
    mrow = mnew;
    const float mc = mnew * C;
    float psum = 0.f;
#pragma unroll
    for (int kc = 0; kc < 4; ++kc) {
      u16x4 pk;
#pragma unroll
      for (int jj = 0; jj < 4; ++jj) {
        const float p = exp2f(s[kc][jj] * C - mc);
        psum += p;
        pk[jj] = f2bf(p);
      }
      *reinterpret_cast<u16x4*>(myp + swzb(lm, kc * 32 + lk * 8)) = pk;
    }
    psum += __shfl_xor(psum, 16, 64);
    psum += __shfl_xor(psum, 32, 64);
    lrow = lrow * alpha + psum;

    // ---- rescale O by alpha of each lane's OUTPUT rows (q = q0+lk*4+jj)
    float a4[4];
#pragma unroll
    for (int jj = 0; jj < 4; ++jj) a4[jj] = __shfl(alpha, lk * 4 + jj, 64);
#pragma unroll
    for (int t = 0; t < 4; ++t)
#pragma unroll
      for (int jj = 0; jj < 4; ++jj) o_acc[t][jj] *= a4[jj];

    // ---- PV: O[q][d] += P * V  (P from LDS in A-layout, V^T b128 reads)
#pragma unroll
    for (int kt = 0; kt < 2; ++kt) {
      const u16x8 pa = *reinterpret_cast<const u16x8*>(myp + swzb(lm, kt * 64 + lk * 16));
#pragma unroll
      for (int t = 0; t < 4; ++t) {
        const u16x8 vf = *reinterpret_cast<const u16x8*>((char*)vt_lds + swzb(t * 16 + lm, kt * 64 + lk * 16));
        o_acc[t] = mfma16(pa, vf, o_acc[t]);
      }
    }
    __syncthreads();
  }

  // epilogue: broadcast l for output rows, divide, store
  float l4[4];
#pragma unroll
  for (int jj = 0; jj < 4; ++jj) l4[jj] = __shfl(lrow, lk * 4 + jj, 64);
#pragma unroll
  for (int t = 0; t < 4; ++t) {
#pragma unroll
    for (int jj = 0; jj < 4; ++jj) {
      const int rowg = q0 + lk * 4 + jj;
      const float val = o_acc[t][jj] / l4[jj];
      ob[((size_t)(b * Sn + rowg)) * Dn + h * HDn + t * 16 + lm] = f2bf(val);
    }
  }
}

extern "C" void kernel_launch(void* const* d_in, const int* in_sizes, int n_in,
                              void* d_out, int out_size, void* d_ws, size_t ws_size,
                              hipStream_t stream) {
  const float* x = (const float*)d_in[0];
  const float* w_attn = (const float*)d_in[1];
  const float* b_attn = (const float*)d_in[2];
  const float* w_proj = (const float*)d_in[3];
  const float* b_proj = (const float*)d_in[4];
  float* out = (float*)d_out;

  u16* ws = (u16*)d_ws;
  u16* xb = ws;                                  // [4096,1024]
  u16* wat = xb + (size_t)4096 * 1024;           // [3072,1024]
  u16* wpt = wat + (size_t)3072 * 1024;          // [1024,1024]
  u16* qb = wpt + (size_t)1024 * 1024;           // [B,H,S,HD]
  u16* kb = qb + (size_t)Bn * Hn * Sn * HDn;
  u16* vb = kb + (size_t)Bn * Hn * Sn * HDn;
  u16* ao = vb + (size_t)Bn * Hn * Sn * HDn;     // [4096,1024]

  k_cvt<<<4096, 256, 0, stream>>>(x, xb, 1048576);
  k_transpose<<<dim3(3072 / 32, 1024 / 32), dim3(32, 8), 0, stream>>>(w_attn, wat, 1024, 3072);
  k_transpose<<<dim3(1024 / 32, 1024 / 32), dim3(32, 8), 0, stream>>>(w_proj, wpt, 1024, 1024);
  k_gemm_bt<<<dim3(3072 / 128, 4096 / 128), 256, 0, stream>>>(xb, wat, 1024, b_attn, qb, kb, vb, nullptr, 0);
  k_attn<<<Bn * Hn * (Sn / 64), 256, 0, stream>>>(qb, kb, vb, ao);
  k_gemm_bt<<<dim3(1024 / 128, 4096 / 128), 256, 0, stream>>>(ao, wpt, 1024, b_proj, nullptr, nullptr, nullptr, out, 1);
}

// Round 5
// 202.795 us; speedup vs baseline: 1.6276x; 1.0157x over previous
//
#include <hip/hip_runtime.h>

// GPT-2 attention block, MI355X/gfx950.
// cvt(x)->bf16 | transpose(w)->bf16 [N,K] | QKV GEMM (2-phase dbuf, scatter) |
// flash attention (swapped QK^T, defer-max, setprio) | proj GEMM (2-phase dbuf)
#define Bn 2
#define Sn 2048
#define Dn 1024
#define Hn 16
#define HDn 64

typedef unsigned short u16;
typedef u16 u16x4 __attribute__((ext_vector_type(4)));
typedef u16 u16x8 __attribute__((ext_vector_type(8)));
typedef __bf16 bf16x8 __attribute__((ext_vector_type(8)));
typedef float f32x4 __attribute__((ext_vector_type(4)));

// native f32->bf16 (RTNE via v_cvt; m240: scalar cast compiles well)
__device__ __forceinline__ u16 cvt1(float f) {
  __bf16 h = (__bf16)f;
  return __builtin_bit_cast(u16, h);
}

__device__ __forceinline__ f32x4 mfma16(u16x8 a, u16x8 b, f32x4 c) {
  return __builtin_amdgcn_mfma_f32_16x16x32_bf16(
      __builtin_bit_cast(bf16x8, a), __builtin_bit_cast(bf16x8, b), c, 0, 0, 0);
}

// XOR swizzle for 128B-stride LDS tiles (attn): conflict-free for
// row-varying-lane b128 reads and the V^T transposed b16 writes.
__device__ __forceinline__ int swzb(int row, int bytecol) {
  return row * 128 + (bytecol ^ ((((row & 7) ^ ((row >> 3) & 7))) << 4));
}

// ---------------- fp32 -> bf16 elementwise (vectorized) ----------------
__global__ __launch_bounds__(256) void k_cvt(const float* __restrict__ in,
                                             u16* __restrict__ out, int n4) {
  int i = blockIdx.x * 256 + threadIdx.x;
  if (i < n4) {
    const float4 v = reinterpret_cast<const float4*>(in)[i];
    u16x4 o = {cvt1(v.x), cvt1(v.y), cvt1(v.z), cvt1(v.w)};
    reinterpret_cast<u16x4*>(out)[i] = o;
  }
}

// ---------------- fp32 [K,N] -> bf16 [N,K] tiled transpose ----------------
__global__ __launch_bounds__(256) void k_transpose(const float* __restrict__ in,
                                                   u16* __restrict__ out,
                                                   int K, int N) {
  __shared__ u16 tile[32][33];
  const int n0 = blockIdx.x * 32, k0 = blockIdx.y * 32;
  const int tx = threadIdx.x, ty = threadIdx.y;
#pragma unroll
  for (int r = 0; r < 4; ++r) {
    const int k = ty * 4 + r;
    tile[k][tx] = cvt1(in[(size_t)(k0 + k) * N + n0 + tx]);
  }
  __syncthreads();
#pragma unroll
  for (int r = 0; r < 4; ++r) {
    const int n = ty * 4 + r;
    out[(size_t)(n0 + n) * K + k0 + tx] = tile[tx][n];
  }
}

// ---------------- bf16 GEMM  C[M,N] = A[M,K] * Bt[N,K]^T ----------------
// 128x128 tile, 4 waves, BK=32, 2-phase double-buffer: issue next tile's
// global_load_lds BEFORE computing current; ONE barrier per K-step (the
// __syncthreads vmcnt-drain then waits on NEXT tile's loads, so staging
// latency hides under this tile's ds_read+MFMA even at 1 block/CU).
__global__ __launch_bounds__(256) void k_gemm_bt(
    const u16* __restrict__ A, const u16* __restrict__ Bt, int K,
    const float* __restrict__ bias, u16* __restrict__ oq, u16* __restrict__ ok,
    u16* __restrict__ ov, float* __restrict__ of, int mode) {
  __shared__ __align__(16) u16 a_lds[2][128 * 32];
  __shared__ __align__(16) u16 b_lds[2][128 * 32];
  const int tid = threadIdx.x;
  const int lane = tid & 63, w = tid >> 6;
  const int wr = w >> 1, wc = w & 1;
  const int lm = lane & 15, lk = lane >> 4;
  const int m0 = blockIdx.y * 128, n0 = blockIdx.x * 128;

  f32x4 acc[4][4] = {};

#define STAGE(d, ko)                                                          \
  {                                                                           \
    _Pragma("unroll") for (int p = 0; p < 2; ++p) {                           \
      const int e = p * 2048 + w * 512 + lane * 8;                            \
      const int row = e >> 5, col = e & 31;                                   \
      __builtin_amdgcn_global_load_lds(                                       \
          (const __attribute__((address_space(1))) void*)(A + (size_t)(m0 + row) * K + (ko) + col), \
          (__attribute__((address_space(3))) void*)(a_lds[d] + p * 2048 + w * 512), \
          16, 0, 0);                                                          \
      __builtin_amdgcn_global_load_lds(                                       \
          (const __attribute__((address_space(1))) void*)(Bt + (size_t)(n0 + row) * K + (ko) + col), \
          (__attribute__((address_space(3))) void*)(b_lds[d] + p * 2048 + w * 512), \
          16, 0, 0);                                                          \
    }                                                                         \
  }

  STAGE(0, 0);
  __syncthreads();
  int cur = 0;
  for (int k0 = 0; k0 < K; k0 += 32) {
    if (k0 + 32 < K) STAGE(cur ^ 1, k0 + 32);
    u16x8 av[4], bv[4];
#pragma unroll
    for (int m = 0; m < 4; ++m)
      av[m] = *reinterpret_cast<const u16x8*>(a_lds[cur] + (wr * 64 + m * 16 + lm) * 32 + lk * 8);
#pragma unroll
    for (int n = 0; n < 4; ++n)
      bv[n] = *reinterpret_cast<const u16x8*>(b_lds[cur] + (wc * 64 + n * 16 + lm) * 32 + lk * 8);
#pragma unroll
    for (int m = 0; m < 4; ++m)
#pragma unroll
      for (int n = 0; n < 4; ++n)
        acc[m][n] = mfma16(av[m], bv[n], acc[m][n]);
    __syncthreads();  // drains vmcnt -> next buffer ready; LDS reads done
    cur ^= 1;
  }
#undef STAGE

#pragma unroll
  for (int m = 0; m < 4; ++m) {
#pragma unroll
    for (int n = 0; n < 4; ++n) {
      const int col = n0 + wc * 64 + n * 16 + lm;
      const float bb = bias[col];
#pragma unroll
      for (int j = 0; j < 4; ++j) {
        const int row = m0 + wr * 64 + m * 16 + lk * 4 + j;
        float val = acc[m][n][j] + bb;
        if (mode == 0) {
          const int which = col >> 10;
          const int h = (col >> 6) & 15, hd = col & 63;
          if (which == 0) val *= 0.125f;
          const int b = row >> 11, s = row & 2047;
          const size_t idx = (((size_t)(b * Hn + h)) * Sn + s) * HDn + hd;
          u16* dst = which == 0 ? oq : (which == 1 ? ok : ov);
          dst[idx] = cvt1(val);
        } else {
          of[(size_t)row * Dn + col] = val;
        }
      }
    }
  }
}

// ---------------- causal flash attention (v3) ----------------
// v2 + T13 defer-max (skip O-rescale when max growth <= 8), T5 setprio
// around MFMA clusters, native bf16 converts.
__global__ __launch_bounds__(256) void k_attn(const u16* __restrict__ qb,
                                              const u16* __restrict__ kb,
                                              const u16* __restrict__ vb,
                                              u16* __restrict__ ob) {
  const int bx = blockIdx.x;
  const int qt = 31 - (bx >> 5);   // longest blocks first
  const int bh = bx & 31;
  const int h = bh & 15, b = bh >> 4;
  const int tid = threadIdx.x, lane = tid & 63, w = tid >> 6;
  const int lm = lane & 15, lk = lane >> 4;
  const int Q0 = qt * 64;
  const int q0 = Q0 + w * 16;
  const size_t head = (size_t)(b * Hn + h) * Sn * HDn;
  const u16* Q = qb + head;
  const u16* Kp = kb + head;
  const u16* Vp = vb + head;

  __shared__ __align__(16) u16 k_lds[64 * 64];
  __shared__ __align__(16) u16 vt_lds[64 * 64];
  __shared__ __align__(16) u16 p_lds[4][16 * 64];
  char* myp = (char*)p_lds[w];

  const int sr = tid >> 2, scb = (tid & 3) * 16;
  const u16* Ksrc = Kp + (size_t)sr * HDn + scb;
  const u16* Vsrc = Vp + (size_t)sr * HDn + scb;

  u16x8 aq[2];
#pragma unroll
  for (int c = 0; c < 2; ++c)
    aq[c] = *reinterpret_cast<const u16x8*>(Q + (size_t)(q0 + lm) * HDn + c * 32 + lk * 8);

  f32x4 o_acc[4] = {};
  float mrow = -1e30f, lrow = 0.f;  // softmax state for q-row q0+lm
  const float C = 1.44269504f;

  const int nk = Q0 + 64;
  u16x8 kreg[2], vreg[2];
  kreg[0] = *reinterpret_cast<const u16x8*>(Ksrc);
  kreg[1] = *reinterpret_cast<const u16x8*>(Ksrc + 8);
  vreg[0] = *reinterpret_cast<const u16x8*>(Vsrc);
  vreg[1] = *reinterpret_cast<const u16x8*>(Vsrc + 8);

  for (int j0 = 0; j0 < nk; j0 += 64) {
    *reinterpret_cast<u16x8*>((char*)k_lds + swzb(sr, scb * 2)) = kreg[0];
    *reinterpret_cast<u16x8*>((char*)k_lds + swzb(sr, scb * 2 + 16)) = kreg[1];
#pragma unroll
    for (int i = 0; i < 8; ++i) {
      *reinterpret_cast<u16*>((char*)vt_lds + swzb(scb + i, sr * 2)) = vreg[0][i];
      *reinterpret_cast<u16*>((char*)vt_lds + swzb(scb + 8 + i, sr * 2)) = vreg[1][i];
    }
    __syncthreads();
    if (j0 + 64 < nk) {
      const u16* kn = Ksrc + (size_t)(j0 + 64) * HDn;
      const u16* vn = Vsrc + (size_t)(j0 + 64) * HDn;
      kreg[0] = *reinterpret_cast<const u16x8*>(kn);
      kreg[1] = *reinterpret_cast<const u16x8*>(kn + 8);
      vreg[0] = *reinterpret_cast<const u16x8*>(vn);
      vreg[1] = *reinterpret_cast<const u16x8*>(vn + 8);
    }

    // ---- QK^T (swapped): lane holds S[q0+lm][j0+kc*16+lk*4+jj]
    f32x4 s[4];
    __builtin_amdgcn_s_setprio(1);
#pragma unroll
    for (int kc = 0; kc < 4; ++kc) {
      const u16x8 kf0 = *reinterpret_cast<const u16x8*>((char*)k_lds + swzb(kc * 16 + lm, lk * 16));
      const u16x8 kf1 = *reinterpret_cast<const u16x8*>((char*)k_lds + swzb(kc * 16 + lm, 64 + lk * 16));
      f32x4 z = {};
      z = mfma16(kf0, aq[0], z);
      s[kc] = mfma16(kf1, aq[1], z);
    }
    __builtin_amdgcn_s_setprio(0);
    if (j0 + 63 > q0) {  // causal mask (diagonal tile only)
#pragma unroll
      for (int kc = 0; kc < 4; ++kc)
#pragma unroll
        for (int jj = 0; jj < 4; ++jj)
          if (j0 + kc * 16 + lk * 4 + jj > q0 + lm) s[kc][jj] = -1e30f;
    }

    // ---- online softmax (lane-local row), defer-max THR=8 ----
    float vmax = -1e30f;
#pragma unroll
    for (int kc = 0; kc < 4; ++kc)
#pragma unroll
      for (int jj = 0; jj < 4; ++jj) vmax = fmaxf(vmax, s[kc][jj]);
    vmax = fmaxf(vmax, __shfl_xor(vmax, 16, 64));
    vmax = fmaxf(vmax, __shfl_xor(vmax, 32, 64));
    if (!__all(vmax - mrow <= 8.0f)) {  // rescale only when max grew
      const float mnew = fmaxf(mrow, vmax);
      const float alpha = exp2f((mrow - mnew) * C);
      mrow = mnew;
      lrow *= alpha;
      float a4[4];
#pragma unroll
      for (int jj = 0; jj < 4; ++jj) a4[jj] = __shfl(alpha, lk * 4 + jj, 64);
#pragma unroll
      for (int t = 0; t < 4; ++t)
#pragma unroll
        for (int jj = 0; jj < 4; ++jj) o_acc[t][jj] *= a4[jj];
    }
    const float mc = mrow * C;
    float psum = 0.f;
#pragma unroll
    for (int kc = 0; kc < 4; ++kc) {
      u16x4 pk;
#pragma unroll
      for (int jj = 0; jj < 4; ++jj) {
        const float p = exp2f(s[kc][jj] * C - mc);
        psum += p;
        pk[jj] = cvt1(p);
      }
      *reinterpret_cast<u16x4*>(myp + swzb(lm, kc * 32 + lk * 8)) = pk;
    }
    psum += __shfl_xor(psum, 16, 64);
    psum += __shfl_xor(psum, 32, 64);
    lrow += psum;

    // ---- PV: O[q][d] += P * V
    __builtin_amdgcn_s_setprio(1);
#pragma unroll
    for (int kt = 0; kt < 2; ++kt) {
      const u16x8 pa = *reinterpret_cast<const u16x8*>(myp + swzb(lm, kt * 64 + lk * 16));
#pragma unroll
      for (int t = 0; t < 4; ++t) {
        const u16x8 vf = *reinterpret_cast<const u16x8*>((char*)vt_lds + swzb(t * 16 + lm, kt * 64 + lk * 16));
        o_acc[t] = mfma16(pa, vf, o_acc[t]);
      }
    }
    __builtin_amdgcn_s_setprio(0);
    __syncthreads();
  }

  float l4[4];
#pragma unroll
  for (int jj = 0; jj < 4; ++jj) l4[jj] = __shfl(lrow, lk * 4 + jj, 64);
#pragma unroll
  for (int t = 0; t < 4; ++t) {
#pragma unroll
    for (int jj = 0; jj < 4; ++jj) {
      const int rowg = q0 + lk * 4 + jj;
      const float val = o_acc[t][jj] / l4[jj];
      ob[((size_t)(b * Sn + rowg)) * Dn + h * HDn + t * 16 + lm] = cvt1(val);
    }
  }
}

extern "C" void kernel_launch(void* const* d_in, const int* in_sizes, int n_in,
                              void* d_out, int out_size, void* d_ws, size_t ws_size,
                              hipStream_t stream) {
  const float* x = (const float*)d_in[0];
  const float* w_attn = (const float*)d_in[1];
  const float* b_attn = (const float*)d_in[2];
  const float* w_proj = (const float*)d_in[3];
  const float* b_proj = (const float*)d_in[4];
  float* out = (float*)d_out;

  u16* ws = (u16*)d_ws;
  u16* xb = ws;                                  // [4096,1024]
  u16* wat = xb + (size_t)4096 * 1024;           // [3072,1024]
  u16* wpt = wat + (size_t)3072 * 1024;          // [1024,1024]
  u16* qb = wpt + (size_t)1024 * 1024;           // [B,H,S,HD]
  u16* kb = qb + (size_t)Bn * Hn * Sn * HDn;
  u16* vb = kb + (size_t)Bn * Hn * Sn * HDn;
  u16* ao = vb + (size_t)Bn * Hn * Sn * HDn;     // [4096,1024]

  k_cvt<<<4096, 256, 0, stream>>>(x, xb, 1048576);
  k_transpose<<<dim3(3072 / 32, 1024 / 32), dim3(32, 8), 0, stream>>>(w_attn, wat, 1024, 3072);
  k_transpose<<<dim3(1024 / 32, 1024 / 32), dim3(32, 8), 0, stream>>>(w_proj, wpt, 1024, 1024);
  k_gemm_bt<<<dim3(3072 / 128, 4096 / 128), 256, 0, stream>>>(xb, wat, 1024, b_attn, qb, kb, vb, nullptr, 0);
  k_attn<<<Bn * Hn * (Sn / 64), 256, 0, stream>>>(qb, kb, vb, ao);
  k_gemm_bt<<<dim3(1024 / 128, 4096 / 128), 256, 0, stream>>>(ao, wpt, 1024, b_proj, nullptr, nullptr, nullptr, out, 1);
}

// Round 7
// 188.713 us; speedup vs baseline: 1.7490x; 1.0746x over previous
//
#include <hip/hip_runtime.h>

// GPT-2 attention block, MI355X/gfx950.
// cvt(x)->bf16 | transpose(w)->bf16 [N,K] | QKV GEMM 128^2/8-wave/BK64 2-phase
// (scatter q*0.125, k row-major, V TRANSPOSED [B,H,HD,S]) | flash attention
// (swapped QK^T, vector V^T staging) | proj GEMM (same structure)
#define Bn 2
#define Sn 2048
#define Dn 1024
#define Hn 16
#define HDn 64

typedef unsigned short u16;
typedef u16 u16x4 __attribute__((ext_vector_type(4)));
typedef u16 u16x8 __attribute__((ext_vector_type(8)));
typedef __bf16 bf16x8 __attribute__((ext_vector_type(8)));
typedef float f32x4 __attribute__((ext_vector_type(4)));

__device__ __forceinline__ u16 cvt1(float f) {
  __bf16 h = (__bf16)f;
  return __builtin_bit_cast(u16, h);
}

__device__ __forceinline__ f32x4 mfma16(u16x8 a, u16x8 b, f32x4 c) {
  return __builtin_amdgcn_mfma_f32_16x16x32_bf16(
      __builtin_bit_cast(bf16x8, a), __builtin_bit_cast(bf16x8, b), c, 0, 0, 0);
}

// XOR swizzle for 128B-stride LDS tiles: each 8-row group spreads a fixed
// 16B column slot across 8 distinct slots -> <=2-way on all our patterns.
__device__ __forceinline__ int xorv(int row) {
  return (row & 7) ^ ((row >> 3) & 7);
}
__device__ __forceinline__ int swzb(int row, int bytecol) {
  return row * 128 + (bytecol ^ (xorv(row) << 4));
}

// ---------------- fp32 -> bf16 elementwise (vectorized) ----------------
__global__ __launch_bounds__(256) void k_cvt(const float* __restrict__ in,
                                             u16* __restrict__ out, int n4) {
  int i = blockIdx.x * 256 + threadIdx.x;
  if (i < n4) {
    const float4 v = reinterpret_cast<const float4*>(in)[i];
    u16x4 o = {cvt1(v.x), cvt1(v.y), cvt1(v.z), cvt1(v.w)};
    reinterpret_cast<u16x4*>(out)[i] = o;
  }
}

// ---------------- fp32 [K,N] -> bf16 [N,K] tiled transpose ----------------
__global__ __launch_bounds__(256) void k_transpose(const float* __restrict__ in,
                                                   u16* __restrict__ out,
                                                   int K, int N) {
  __shared__ u16 tile[32][33];
  const int n0 = blockIdx.x * 32, k0 = blockIdx.y * 32;
  const int tx = threadIdx.x, ty = threadIdx.y;
#pragma unroll
  for (int r = 0; r < 4; ++r) {
    const int k = ty * 4 + r;
    tile[k][tx] = cvt1(in[(size_t)(k0 + k) * N + n0 + tx]);
  }
  __syncthreads();
#pragma unroll
  for (int r = 0; r < 4; ++r) {
    const int n = ty * 4 + r;
    out[(size_t)(n0 + n) * K + k0 + tx] = tile[tx][n];
  }
}

// ---------------- bf16 GEMM  C[M,N] = A[M,K] * Bt[N,K]^T ----------------
// 128x128 tile, 8 waves (2 wr x 4 wc), BK=64, swizzled LDS, 2-phase:
// stage tile t+1 (16B global_load_lds, pre-swizzled source, linear dest)
// before computing tile t; one barrier per K-tile.
// mode 0: qkv epilogue (bias; q*=0.125 -> [B,H,S,HD]; k -> [B,H,S,HD];
//         v -> TRANSPOSED [B,H,HD,S], vectorized 8B stores)
// mode 1: proj epilogue (bias, fp32 out row-major)
__global__ __launch_bounds__(512) void k_gemm2(
    const u16* __restrict__ A, const u16* __restrict__ Bt, int K,
    const float* __restrict__ bias, u16* __restrict__ oq, u16* __restrict__ ok,
    u16* __restrict__ ov, float* __restrict__ of, int mode) {
  __shared__ __align__(16) u16 a_lds[2][8192];  // [128 rows][64 k] swizzled
  __shared__ __align__(16) u16 b_lds[2][8192];
  const int tid = threadIdx.x;
  const int lane = tid & 63, w = tid >> 6;
  const int wr = w >> 2, wc = w & 3;
  const int lm = lane & 15, lk = lane >> 4;
  const int m0 = blockIdx.y * 128, n0 = blockIdx.x * 128;
  const int NT = K >> 6;

  // staging map: load p in {0,1}: LDS byte lin = p*8192 + tid*16 (linear,
  // wave-uniform base + lane*16). Source element col is inverse-swizzled.
  const int srow0 = tid >> 3;            // lin>>7 for p=0 (p=1 adds 64)
  const int scb = (tid & 7) * 16;        // byte col within row

  f32x4 acc[4][2] = {};

#define STAGE2(d, kt)                                                         \
  {                                                                           \
    _Pragma("unroll") for (int p = 0; p < 2; ++p) {                           \
      const int row = p * 64 + srow0;                                         \
      const int col = (scb ^ (xorv(row) << 4)) >> 1;                          \
      __builtin_amdgcn_global_load_lds(                                       \
          (const __attribute__((address_space(1))) void*)(A + (size_t)(m0 + row) * K + (kt) * 64 + col), \
          (__attribute__((address_space(3))) void*)(a_lds[d] + p * 4096 + tid * 8), \
          16, 0, 0);                                                          \
      __builtin_amdgcn_global_load_lds(                                       \
          (const __attribute__((address_space(1))) void*)(Bt + (size_t)(n0 + row) * K + (kt) * 64 + col), \
          (__attribute__((address_space(3))) void*)(b_lds[d] + p * 4096 + tid * 8), \
          16, 0, 0);                                                          \
    }                                                                         \
  }

  STAGE2(0, 0);
  __syncthreads();

  for (int t = 0; t < NT; ++t) {
    const int cur = t & 1;
    if (t + 1 < NT) STAGE2(cur ^ 1, t + 1);  // flies over this tile's compute
    u16x8 av[4][2], bv[2][2];
#pragma unroll
    for (int m = 0; m < 4; ++m)
#pragma unroll
      for (int kk = 0; kk < 2; ++kk)
        av[m][kk] = *reinterpret_cast<const u16x8*>(
            (char*)a_lds[cur] + swzb(wr * 64 + m * 16 + lm, kk * 64 + lk * 16));
#pragma unroll
    for (int n = 0; n < 2; ++n)
#pragma unroll
      for (int kk = 0; kk < 2; ++kk)
        bv[n][kk] = *reinterpret_cast<const u16x8*>(
            (char*)b_lds[cur] + swzb(wc * 32 + n * 16 + lm, kk * 64 + lk * 16));
    __builtin_amdgcn_s_setprio(1);
#pragma unroll
    for (int kk = 0; kk < 2; ++kk)
#pragma unroll
      for (int m = 0; m < 4; ++m)
#pragma unroll
        for (int n = 0; n < 2; ++n)
          acc[m][n] = mfma16(av[m][kk], bv[n][kk], acc[m][n]);
    __builtin_amdgcn_s_setprio(0);
    __syncthreads();  // drains vmcnt (t+1 loads mostly landed under compute)
  }
#undef STAGE2

#pragma unroll
  for (int m = 0; m < 4; ++m) {
#pragma unroll
    for (int n = 0; n < 2; ++n) {
      const int col = n0 + wc * 32 + n * 16 + lm;
      const float bb = bias[col];
      const int row0 = m0 + wr * 64 + m * 16 + lk * 4;
      if (mode == 0) {
        const int which = col >> 10;
        const int h = (col >> 6) & 15, hd = col & 63;
        const int b = row0 >> 11, s0 = row0 & 2047;
        if (which == 2) {  // V transposed: [B,H,HD,S], 4 consecutive s
          u16x4 pk;
#pragma unroll
          for (int j = 0; j < 4; ++j) pk[j] = cvt1(acc[m][n][j] + bb);
          *reinterpret_cast<u16x4*>(
              ov + ((size_t)(b * Hn + h) * HDn + hd) * Sn + s0) = pk;
        } else {
          u16* dst = which == 0 ? oq : ok;
          const float sc = which == 0 ? 0.125f : 1.0f;
#pragma unroll
          for (int j = 0; j < 4; ++j)
            dst[((size_t)(b * Hn + h) * Sn + s0 + j) * HDn + hd] =
                cvt1((acc[m][n][j] + bb) * sc);
        }
      } else {
#pragma unroll
        for (int j = 0; j < 4; ++j)
          of[(size_t)(row0 + j) * Dn + col] = acc[m][n][j] + bb;
      }
    }
  }
}

// ---------------- causal flash attention (v4) ----------------
// v3 + V already transposed in global ([B,H,HD,S]) -> V^T staging is two
// vector b128 LDS writes per thread (was 16 scalar writes + addr math).
__global__ __launch_bounds__(256) void k_attn(const u16* __restrict__ qb,
                                              const u16* __restrict__ kb,
                                              const u16* __restrict__ vtb,
                                              u16* __restrict__ ob) {
  const int bx = blockIdx.x;
  const int qt = 31 - (bx >> 5);   // longest blocks first
  const int bh = bx & 31;
  const int h = bh & 15, b = bh >> 4;
  const int tid = threadIdx.x, lane = tid & 63, w = tid >> 6;
  const int lm = lane & 15, lk = lane >> 4;
  const int Q0 = qt * 64;
  const int q0 = Q0 + w * 16;
  const size_t head = (size_t)(b * Hn + h) * Sn * HDn;
  const u16* Q = qb + head;
  const u16* Kp = kb + head;
  const u16* Vt = vtb + head;  // [HD][S] within head

  __shared__ __align__(16) u16 k_lds[64 * 64];
  __shared__ __align__(16) u16 vt_lds[64 * 64];
  __shared__ __align__(16) u16 p_lds[4][16 * 64];
  char* myp = (char*)p_lds[w];

  const int sr = tid >> 2, scb = (tid & 3) * 16;
  const u16* Ksrc = Kp + (size_t)sr * HDn + scb;   // K row sr, hd scb..
  const u16* Vsrc = Vt + (size_t)sr * Sn + scb;    // V^T row d=sr, s offset scb

  u16x8 aq[2];
#pragma unroll
  for (int c = 0; c < 2; ++c)
    aq[c] = *reinterpret_cast<const u16x8*>(Q + (size_t)(q0 + lm) * HDn + c * 32 + lk * 8);

  f32x4 o_acc[4] = {};
  float mrow = -1e30f, lrow = 0.f;
  const float C = 1.44269504f;

  const int nk = Q0 + 64;
  u16x8 kreg[2], vreg[2];
  kreg[0] = *reinterpret_cast<const u16x8*>(Ksrc);
  kreg[1] = *reinterpret_cast<const u16x8*>(Ksrc + 8);
  vreg[0] = *reinterpret_cast<const u16x8*>(Vsrc);
  vreg[1] = *reinterpret_cast<const u16x8*>(Vsrc + 8);

  for (int j0 = 0; j0 < nk; j0 += 64) {
    *reinterpret_cast<u16x8*>((char*)k_lds + swzb(sr, scb * 2)) = kreg[0];
    *reinterpret_cast<u16x8*>((char*)k_lds + swzb(sr, scb * 2 + 16)) = kreg[1];
    *reinterpret_cast<u16x8*>((char*)vt_lds + swzb(sr, scb * 2)) = vreg[0];
    *reinterpret_cast<u16x8*>((char*)vt_lds + swzb(sr, scb * 2 + 16)) = vreg[1];
    __syncthreads();
    if (j0 + 64 < nk) {
      const u16* kn = Ksrc + (size_t)(j0 + 64) * HDn;
      const u16* vn = Vsrc + (j0 + 64);
      kreg[0] = *reinterpret_cast<const u16x8*>(kn);
      kreg[1] = *reinterpret_cast<const u16x8*>(kn + 8);
      vreg[0] = *reinterpret_cast<const u16x8*>(vn);
      vreg[1] = *reinterpret_cast<const u16x8*>(vn + 8);
    }

    // ---- QK^T (swapped): lane holds S[q0+lm][j0+kc*16+lk*4+jj]
    f32x4 s[4];
    __builtin_amdgcn_s_setprio(1);
#pragma unroll
    for (int kc = 0; kc < 4; ++kc) {
      const u16x8 kf0 = *reinterpret_cast<const u16x8*>((char*)k_lds + swzb(kc * 16 + lm, lk * 16));
      const u16x8 kf1 = *reinterpret_cast<const u16x8*>((char*)k_lds + swzb(kc * 16 + lm, 64 + lk * 16));
      f32x4 z = {};
      z = mfma16(kf0, aq[0], z);
      s[kc] = mfma16(kf1, aq[1], z);
    }
    __builtin_amdgcn_s_setprio(0);
    if (j0 + 63 > q0) {
#pragma unroll
      for (int kc = 0; kc < 4; ++kc)
#pragma unroll
        for (int jj = 0; jj < 4; ++jj)
          if (j0 + kc * 16 + lk * 4 + jj > q0 + lm) s[kc][jj] = -1e30f;
    }

    // ---- online softmax (lane-local row), defer-max THR=8 ----
    float vmax = -1e30f;
#pragma unroll
    for (int kc = 0; kc < 4; ++kc)
#pragma unroll
      for (int jj = 0; jj < 4; ++jj) vmax = fmaxf(vmax, s[kc][jj]);
    vmax = fmaxf(vmax, __shfl_xor(vmax, 16, 64));
    vmax = fmaxf(vmax, __shfl_xor(vmax, 32, 64));
    if (!__all(vmax - mrow <= 8.0f)) {
      const float mnew = fmaxf(mrow, vmax);
      const float alpha = exp2f((mrow - mnew) * C);
      mrow = mnew;
      lrow *= alpha;
      float a4[4];
#pragma unroll
      for (int jj = 0; jj < 4; ++jj) a4[jj] = __shfl(alpha, lk * 4 + jj, 64);
#pragma unroll
      for (int t = 0; t < 4; ++t)
#pragma unroll
        for (int jj = 0; jj < 4; ++jj) o_acc[t][jj] *= a4[jj];
    }
    const float mc = mrow * C;
    float psum = 0.f;
#pragma unroll
    for (int kc = 0; kc < 4; ++kc) {
      u16x4 pk;
#pragma unroll
      for (int jj = 0; jj < 4; ++jj) {
        const float p = exp2f(s[kc][jj] * C - mc);
        psum += p;
        pk[jj] = cvt1(p);
      }
      *reinterpret_cast<u16x4*>(myp + swzb(lm, kc * 32 + lk * 8)) = pk;
    }
    psum += __shfl_xor(psum, 16, 64);
    psum += __shfl_xor(psum, 32, 64);
    lrow += psum;

    // ---- PV: O[q][d] += P * V
    __builtin_amdgcn_s_setprio(1);
#pragma unroll
    for (int kt = 0; kt < 2; ++kt) {
      const u16x8 pa = *reinterpret_cast<const u16x8*>(myp + swzb(lm, kt * 64 + lk * 16));
#pragma unroll
      for (int t = 0; t < 4; ++t) {
        const u16x8 vf = *reinterpret_cast<const u16x8*>((char*)vt_lds + swzb(t * 16 + lm, kt * 64 + lk * 16));
        o_acc[t] = mfma16(pa, vf, o_acc[t]);
      }
    }
    __builtin_amdgcn_s_setprio(0);
    __syncthreads();
  }

  float l4[4];
#pragma unroll
  for (int jj = 0; jj < 4; ++jj) l4[jj] = __shfl(lrow, lk * 4 + jj, 64);
#pragma unroll
  for (int t = 0; t < 4; ++t) {
#pragma unroll
    for (int jj = 0; jj < 4; ++jj) {
      const int rowg = q0 + lk * 4 + jj;
      const float val = o_acc[t][jj] / l4[jj];
      ob[((size_t)(b * Sn + rowg)) * Dn + h * HDn + t * 16 + lm] = cvt1(val);
    }
  }
}

extern "C" void kernel_launch(void* const* d_in, const int* in_sizes, int n_in,
                              void* d_out, int out_size, void* d_ws, size_t ws_size,
                              hipStream_t stream) {
  const float* x = (const float*)d_in[0];
  const float* w_attn = (const float*)d_in[1];
  const float* b_attn = (const float*)d_in[2];
  const float* w_proj = (const float*)d_in[3];
  const float* b_proj = (const float*)d_in[4];
  float* out = (float*)d_out;

  u16* ws = (u16*)d_ws;
  u16* xb = ws;                                  // [4096,1024]
  u16* wat = xb + (size_t)4096 * 1024;           // [3072,1024]
  u16* wpt = wat + (size_t)3072 * 1024;          // [1024,1024]
  u16* qb = wpt + (size_t)1024 * 1024;           // [B,H,S,HD]
  u16* kb = qb + (size_t)Bn * Hn * Sn * HDn;     // [B,H,S,HD]
  u16* vtb = kb + (size_t)Bn * Hn * Sn * HDn;    // [B,H,HD,S] (transposed!)
  u16* ao = vtb + (size_t)Bn * Hn * Sn * HDn;    // [4096,1024]

  k_cvt<<<4096, 256, 0, stream>>>(x, xb, 1048576);
  k_transpose<<<dim3(3072 / 32, 1024 / 32), dim3(32, 8), 0, stream>>>(w_attn, wat, 1024, 3072);
  k_transpose<<<dim3(1024 / 32, 1024 / 32), dim3(32, 8), 0, stream>>>(w_proj, wpt, 1024, 1024);
  k_gemm2<<<dim3(3072 / 128, 4096 / 128), 512, 0, stream>>>(xb, wat, 1024, b_attn, qb, kb, vtb, nullptr, 0);
  k_attn<<<Bn * Hn * (Sn / 64), 256, 0, stream>>>(qb, kb, vtb, ao);
  k_gemm2<<<dim3(1024 / 128, 4096 / 128), 512, 0, stream>>>(ao, wpt, 1024, b_proj, nullptr, nullptr, nullptr, out, 1);
}